// Round 5
// baseline (237.294 us; speedup 1.0000x reference)
//
#include <hip/hip_runtime.h>
#include <stdint.h>

#pragma clang fp contract(off)

// ---------------------------------------------------------------------------
// Binary ConvBlock, matched to an fp32 numpy reference:
//   - stage 1: conv1x1(x, sgn w11): SEQUENTIAL fp32 sum over ci=0..255
//     ascending (bit-identical to BLAS sgemm's k-chain), fp32 BN threshold.
//   - stages 2-4: exact-integer popcount convs (fp32-exact in any order),
//     fp32 BN threshold with numpy's exact op order:
//       inv = g / sqrt(v + 1e-4f);  beta = b - m*inv;  val = y*inv + beta
//     (each op correctly rounded fp32, no contraction).
// B=16, Cin=256, down=64, up=256, H=W=56. 3136 = 56*56 = 49*64.
// ---------------------------------------------------------------------------

#define HW_   3136          // 56*56

// workspace layout (bytes, 16-aligned)
#define OFF_W1B    0         // 256 u64
#define OFF_W31B   2048      // 2304 u64 ([co][tap])
#define OFF_W12B   20480     // 256 u64  ([co][k])
#define OFF_W32B   22528     // 2304 u64
#define OFF_IV11   40960     // 64 float2
#define OFF_IV31   41472     // 256 float2
#define OFF_IV12   43520     // 64 float2
#define OFF_IV32   44032     // 256 float2
#define OFF_A1     46080     // 50176 u64
#define OFF_H      447488    // 50176*4 u64
#define OFF_A2     2053120   // 50176 u64
#define OFF_S      2454528   // 50176*4 u64

__device__ inline float2 mk_ivbt(float g, float b, float m, float v) {
    float inv  = __fdiv_rn(g, __fsqrt_rn(__fadd_rn(v, 1e-4f)));
    float beta = __fsub_rn(b, __fmul_rn(m, inv));
    return make_float2(inv, beta);
}

// --------------------------- K0: pack weights ------------------------------
__global__ __launch_bounds__(256) void k0_prep(
    const float* __restrict__ w11, const float* __restrict__ w31,
    const float* __restrict__ w12, const float* __restrict__ w32,
    const float* __restrict__ g11, const float* __restrict__ b11,
    const float* __restrict__ m11, const float* __restrict__ v11,
    const float* __restrict__ g31, const float* __restrict__ b31,
    const float* __restrict__ m31, const float* __restrict__ v31,
    const float* __restrict__ g12, const float* __restrict__ b12,
    const float* __restrict__ m12, const float* __restrict__ v12,
    const float* __restrict__ g32, const float* __restrict__ b32,
    const float* __restrict__ m32, const float* __restrict__ v32,
    uint64_t* __restrict__ W1b, uint64_t* __restrict__ W31b,
    uint64_t* __restrict__ W12b, uint64_t* __restrict__ W32b,
    float2* __restrict__ iv11, float2* __restrict__ iv31,
    float2* __restrict__ iv12, float2* __restrict__ iv32)
{
    int t = blockIdx.x * 256 + threadIdx.x;
    if (t < 256) {                       // W1b[ci]: bit j = sign(w11[j][ci])
        int ci = t;
        uint64_t bits = 0;
        for (int j = 0; j < 64; ++j)
            bits |= (uint64_t)(w11[j * 256 + ci] >= 0.f) << j;
        W1b[ci] = bits;
    } else if (t < 2560) {               // W31b[co*9+tap]: bit ci
        int i = t - 256, co = i / 9, tap = i % 9;
        uint64_t bits = 0;
        for (int ci = 0; ci < 64; ++ci)
            bits |= (uint64_t)(w31[(co * 64 + ci) * 9 + tap] >= 0.f) << ci;
        W31b[i] = bits;
    } else if (t < 2816) {               // W12b[co*4+k]: bit ci'
        int i = t - 2560, co = i >> 2, k = i & 3;
        uint64_t bits = 0;
        for (int ci = 0; ci < 64; ++ci)
            bits |= (uint64_t)(w12[co * 256 + k * 64 + ci] >= 0.f) << ci;
        W12b[i] = bits;
    } else if (t < 5120) {               // W32b
        int i = t - 2816, co = i / 9, tap = i % 9;
        uint64_t bits = 0;
        for (int ci = 0; ci < 64; ++ci)
            bits |= (uint64_t)(w32[(co * 64 + ci) * 9 + tap] >= 0.f) << ci;
        W32b[i] = bits;
    } else if (t < 5760) {               // BN (inv, beta) in fp32, np op order
        int i = t - 5120;
        if (i < 64)        iv11[i]       = mk_ivbt(g11[i],       b11[i],       m11[i],       v11[i]);
        else if (i < 320)  iv31[i - 64]  = mk_ivbt(g31[i - 64],  b31[i - 64],  m31[i - 64],  v31[i - 64]);
        else if (i < 384)  iv12[i - 320] = mk_ivbt(g12[i - 320], b12[i - 320], m12[i - 320], v12[i - 320]);
        else               iv32[i - 384] = mk_ivbt(g32[i - 384], b32[i - 384], m32[i - 384], v32[i - 384]);
    }
}

// ------------- K1: fp32 SEQUENTIAL conv1x1 (x * sgn w11) + sign ------------
// grid 784 (= 16 b * 49 pixel-chunks), block 256 = 64 pixels (l) x 4 groups (g).
// Group g owns output channels [16g,16g+16). Each accumulator is one
// sequential fp32 chain over ci = 0..255 ascending (matches BLAS k-chain).
__global__ __launch_bounds__(256) void k1_conv1(
    const float* __restrict__ x, const uint64_t* __restrict__ W1b,
    const float2* __restrict__ ivbt, uint64_t* __restrict__ A1)
{
    __shared__ float xs[4][64];
    __shared__ unsigned short sh[64][4];

    const int t = threadIdx.x;
    const int l = t & 63;          // pixel within chunk
    const int g = t >> 6;          // channel group 0..3
    const int tile = blockIdx.x;   // 784 = 16 * 49
    const int b = tile / 49;
    const int hw0 = (tile % 49) * 64;
    const size_t xbase = (size_t)b * 256 * HW_ + hw0;

    float acc[16];
#pragma unroll
    for (int jj = 0; jj < 16; ++jj) acc[jj] = 0.0f;

    for (int cb = 0; cb < 256; cb += 4) {
        xs[g][l] = x[xbase + (size_t)(cb + g) * HW_ + l];
        __syncthreads();
#pragma unroll
        for (int c2 = 0; c2 < 4; ++c2) {          // ci = cb + c2, ascending
            float xv = xs[c2][l];
            unsigned wbits = (unsigned)(W1b[cb + c2] >> (g * 16)) & 0xFFFFu;
#pragma unroll
            for (int jj = 0; jj < 16; ++jj)
                acc[jj] = __fadd_rn(acc[jj], ((wbits >> jj) & 1u) ? xv : -xv);
        }
        __syncthreads();
    }

    unsigned short bits16 = 0;
#pragma unroll
    for (int jj = 0; jj < 16; ++jj) {
        float2 ib = ivbt[g * 16 + jj];
        float val = __fadd_rn(__fmul_rn(acc[jj], ib.x), ib.y);
        bits16 |= (unsigned short)((val >= 0.0f) ? (1u << jj) : 0u);
    }
    sh[l][g] = bits16;
    __syncthreads();
    if (g == 0) {
        uint64_t w0 = (uint64_t)sh[l][0]
                    | ((uint64_t)sh[l][1] << 16)
                    | ((uint64_t)sh[l][2] << 32)
                    | ((uint64_t)sh[l][3] << 48);
        A1[tile * 64 + l] = w0;
    }
}

// --------- K2/K4a: binary conv3x3 (64ch in bits -> 256ch bits) -------------
// grid 3136 (tile*4+quarter), block 64. MERGE: out = Hin | result (quant_add).
template <bool MERGE>
__global__ __launch_bounds__(64) void k_conv3(
    const uint64_t* __restrict__ A, const uint64_t* __restrict__ Wb,
    const float2* __restrict__ ivbt, const uint64_t* __restrict__ Hin,
    uint64_t* __restrict__ Out)
{
    const int q = blockIdx.x & 3;
    const int tile = blockIdx.x >> 2;
    const int l = threadIdx.x;
    const int b = tile / 49;
    const int hw = (tile % 49) * 64 + l;
    const int h = hw / 56, w = hw % 56;
    const uint64_t* Ab = A + b * HW_;

    uint64_t a[9];
    bool v[9];
#pragma unroll
    for (int ky = 0; ky < 3; ++ky)
#pragma unroll
        for (int kx = 0; kx < 3; ++kx) {
            int ih = h + ky - 1, iw = w + kx - 1;
            int tt = ky * 3 + kx;
            bool ok = ((unsigned)ih < 56u) && ((unsigned)iw < 56u);
            v[tt] = ok;
            a[tt] = ok ? Ab[ih * 56 + iw] : 0ull;
        }

    uint64_t bits = 0;
#pragma unroll 4
    for (int jo = 0; jo < 64; ++jo) {
        int co = q * 64 + jo;
        const uint64_t* wp = Wb + co * 9;
        int y = 0;
#pragma unroll
        for (int tt = 0; tt < 9; ++tt)
            y += v[tt] ? (64 - 2 * (int)__popcll(a[tt] ^ wp[tt])) : 0;
        float2 ib = ivbt[co];
        float val = __fadd_rn(__fmul_rn((float)y, ib.x), ib.y);
        bits |= (uint64_t)(val >= 0.0f) << jo;
    }
    uint64_t outv = bits;
    size_t oidx = (size_t)(b * HW_ + hw) * 4 + q;
    if (MERGE) outv |= Hin[oidx];
    Out[oidx] = outv;
}

// ------------- K3: binary conv1x1 256->64 (bits -> bits) -------------------
__global__ __launch_bounds__(256) void k3_conv1b(
    const uint64_t* __restrict__ H, const uint64_t* __restrict__ W12b,
    const float2* __restrict__ ivbt, uint64_t* __restrict__ A2)
{
    int p = blockIdx.x * 256 + threadIdx.x;   // < 50176
    const uint64_t* hp = H + (size_t)p * 4;
    uint64_t h0 = hp[0], h1 = hp[1], h2 = hp[2], h3 = hp[3];
    uint64_t bits = 0;
#pragma unroll 4
    for (int co = 0; co < 64; ++co) {
        const uint64_t* wp = W12b + co * 4;
        int s = __popcll(h0 ^ wp[0]) + __popcll(h1 ^ wp[1]) +
                __popcll(h2 ^ wp[2]) + __popcll(h3 ^ wp[3]);
        int y = 256 - 2 * s;
        float2 ib = ivbt[co];
        float val = __fadd_rn(__fmul_rn((float)y, ib.x), ib.y);
        bits |= (uint64_t)(val >= 0.0f) << co;
    }
    A2[p] = bits;
}

// ------------- K4b: OR-pool 2x2 + write +-1.0f -----------------------------
__global__ __launch_bounds__(256) void k4b_pool(
    const uint64_t* __restrict__ S, float* __restrict__ out)
{
    int o = blockIdx.x * 256 + threadIdx.x;   // < 16*256*28*28 = 3211264
    int ow = o % 28;
    int t = o / 28;
    int oh = t % 28; t /= 28;
    int co = t % 256;
    int b = t / 256;
    int k = co >> 6, j = co & 63;
    const uint64_t* Sp = S + ((size_t)(b * 56 + 2 * oh) * 56 + 2 * ow) * 4 + k;
    uint64_t s = Sp[0] | Sp[4] | Sp[224] | Sp[228];
    out[o] = ((s >> j) & 1) ? 1.0f : -1.0f;
}

// ---------------------------------------------------------------------------
extern "C" void kernel_launch(void* const* d_in, const int* in_sizes, int n_in,
                              void* d_out, int out_size, void* d_ws, size_t ws_size,
                              hipStream_t stream)
{
    const float* x   = (const float*)d_in[0];
    const float* w11 = (const float*)d_in[1];
    const float* w31 = (const float*)d_in[2];
    const float* w12 = (const float*)d_in[3];
    const float* w32 = (const float*)d_in[4];
    const float* g11 = (const float*)d_in[5];
    const float* b11 = (const float*)d_in[6];
    const float* m11 = (const float*)d_in[7];
    const float* v11 = (const float*)d_in[8];
    const float* g31 = (const float*)d_in[9];
    const float* b31 = (const float*)d_in[10];
    const float* m31 = (const float*)d_in[11];
    const float* v31 = (const float*)d_in[12];
    const float* g12 = (const float*)d_in[13];
    const float* b12 = (const float*)d_in[14];
    const float* m12 = (const float*)d_in[15];
    const float* v12 = (const float*)d_in[16];
    const float* g32 = (const float*)d_in[17];
    const float* b32 = (const float*)d_in[18];
    const float* m32 = (const float*)d_in[19];
    const float* v32 = (const float*)d_in[20];

    char* ws = (char*)d_ws;
    uint64_t* W1b  = (uint64_t*)(ws + OFF_W1B);
    uint64_t* W31b = (uint64_t*)(ws + OFF_W31B);
    uint64_t* W12b = (uint64_t*)(ws + OFF_W12B);
    uint64_t* W32b = (uint64_t*)(ws + OFF_W32B);
    float2* iv11 = (float2*)(ws + OFF_IV11);
    float2* iv31 = (float2*)(ws + OFF_IV31);
    float2* iv12 = (float2*)(ws + OFF_IV12);
    float2* iv32 = (float2*)(ws + OFF_IV32);
    uint64_t* A1 = (uint64_t*)(ws + OFF_A1);
    uint64_t* Hb = (uint64_t*)(ws + OFF_H);
    uint64_t* A2 = (uint64_t*)(ws + OFF_A2);
    uint64_t* Sb = (uint64_t*)(ws + OFF_S);

    k0_prep<<<dim3(23), dim3(256), 0, stream>>>(
        w11, w31, w12, w32,
        g11, b11, m11, v11, g31, b31, m31, v31,
        g12, b12, m12, v12, g32, b32, m32, v32,
        W1b, W31b, W12b, W32b, iv11, iv31, iv12, iv32);

    k1_conv1<<<dim3(784), dim3(256), 0, stream>>>(x, W1b, iv11, A1);

    k_conv3<false><<<dim3(3136), dim3(64), 0, stream>>>(A1, W31b, iv31, (const uint64_t*)nullptr, Hb);

    k3_conv1b<<<dim3(196), dim3(256), 0, stream>>>(Hb, W12b, iv12, A2);

    k_conv3<true><<<dim3(3136), dim3(64), 0, stream>>>(A2, W32b, iv32, Hb, Sb);

    k4b_pool<<<dim3(12544), dim3(256), 0, stream>>>(Sb, (float*)d_out);
}